// Round 1
// baseline (1382.255 us; speedup 1.0000x reference)
//
#include <hip/hip_runtime.h>

// Problem constants
#define D 8
#define L 12
#define C 9
#define W 128
#define B 4096
#define EPS 1e-5f

// Workspace layout (in floats)
//   [0,18)            stats: sum[9], sumsq[9]   (must be zeroed each launch)
//   [32, 32+20736)    w1eff: folded conv1 weights [D][32][81]
//   [20768, +256)     b1eff: folded conv1 bias   [D][32]
//   [21024, +393216)  pd: per-domain fc outputs  [D][B][12]
#define OFF_STATS 0
#define OFF_W1E   32
#define OFF_B1E   (OFF_W1E + D*32*81)
#define OFF_PD    (OFF_B1E + D*32)

// ---------------------------------------------------------------------------
// Kernel 1: per-channel sum / sumsq over x (B,C,W). Channel stats shared by
// all domains (vmap has in_axes=None on x).
// grid = (9*64), block = 256. blockIdx: c = bx%9, slice = bx/9.
// ---------------------------------------------------------------------------
__global__ void stats_kernel(const float* __restrict__ x, float* __restrict__ ws) {
    const int c = blockIdx.x % 9;
    const int slice = blockIdx.x / 9;          // 0..63
    const int t = threadIdx.x;
    const int w4 = t & 31;                     // float4 slot within channel (32 per ch)
    const int br = t >> 5;                     // 0..7
    const float4* x4 = (const float4*)x;       // row = 288 float4, channel = 32 float4
    float s = 0.f, s2 = 0.f;
    for (int b = slice * 8 + br; b < B; b += 64 * 8) {
        float4 v = x4[(size_t)b * 288 + c * 32 + w4];
        s  += v.x + v.y + v.z + v.w;
        s2 += v.x * v.x + v.y * v.y + v.z * v.z + v.w * v.w;
    }
    for (int off = 32; off >= 1; off >>= 1) {
        s  += __shfl_down(s, off);
        s2 += __shfl_down(s2, off);
    }
    if ((t & 63) == 0) {
        atomicAdd(&ws[OFF_STATS + c], s);
        atomicAdd(&ws[OFF_STATS + 9 + c], s2);
    }
}

// ---------------------------------------------------------------------------
// Kernel 2: fold batchnorm into conv1 weights/bias.
//   xn = x*g + bt  with g = gamma*rsqrt(var+eps), bt = beta - g*mean
//   w1eff[o,c,k] = w1[o,c,k]*g[c];  b1eff[o] = b1[o] + sum_{c,k} w1[o,c,k]*bt[c]
// 1 block, 256 threads = 8 d * 32 o.
// ---------------------------------------------------------------------------
__global__ void fold_kernel(const float* __restrict__ w1, const float* __restrict__ b1,
                            const float* __restrict__ gamma, const float* __restrict__ beta,
                            float* __restrict__ ws) {
    const int t = threadIdx.x;
    const int d = t >> 5, o = t & 31;
    const float N = (float)B * (float)W;
    float bias = b1[d * 32 + o];
    for (int c = 0; c < 9; c++) {
        float m  = ws[OFF_STATS + c] / N;
        float vv = ws[OFF_STATS + 9 + c] / N - m * m;
        float inv = rsqrtf(vv + EPS);
        float g  = gamma[d * 9 + c] * inv;
        float bt = beta[d * 9 + c] - g * m;
        for (int k = 0; k < 9; k++) {
            float wv = w1[(d * 32 + o) * 81 + c * 9 + k];
            ws[OFF_W1E + (d * 32 + o) * 81 + c * 9 + k] = wv * g;
            bias += wv * bt;
        }
    }
    ws[OFF_B1E + d * 32 + o] = bias;
}

// ---------------------------------------------------------------------------
// Kernel 3: the branch. One block = (2 batch rows) x (1 domain).
// grid = (B/2, D), block = 256 (4 waves).
//
// Phase layout (all weights fetched via wave-uniform addresses -> scalar loads
// on the parallel scalar pipe; activations stay in LDS/registers):
//   conv1: wave = (b, o-half of 16); lane = pooled position p<60.
//          acc0/acc1 = raw 2p,2p+1; pool+relu folded: relu(max(a0,a1)+bias).
//   conv2: wave = 16 o's; lane = b*26 + pooled p (52 active lanes).
//   fc:    t<192: (l,b) x 8 chunks of 208, float4 dot, shuffle-8 reduce.
// LDS = 37.9 KB -> 4 blocks/CU.
// ---------------------------------------------------------------------------
__global__ __launch_bounds__(256, 4)
void branch_kernel(const float* __restrict__ x, const float* __restrict__ w2,
                   const float* __restrict__ b2, const float* __restrict__ fcw,
                   const float* __restrict__ fcb, const float* __restrict__ ws,
                   float* __restrict__ pd) {
    const int t = threadIdx.x;
    const int lane = t & 63;
    const int wid = __builtin_amdgcn_readfirstlane(t >> 6);   // force wave-uniform
    const int d = blockIdx.y;
    const int b0 = blockIdx.x * 2;

    __shared__ float xs[2 * 9 * 128];    // 2304 floats
    __shared__ float h1p[2 * 32 * 60];   // 3840 floats
    __shared__ float h2p[2 * 64 * 26];   // 3328 floats

    // ---- stage x (2 rows, contiguous) ----
    {
        const float4* xg = (const float4*)(x + (size_t)b0 * (C * W));
        float4* xl = (float4*)xs;
        for (int i = t; i < 576; i += 256) xl[i] = xg[i];
    }
    __syncthreads();

    // ---- conv1 + relu + maxpool2 ----
    {
        const int bsub = wid & 1;
        const int obase = (wid >> 1) * 16;
        const int p = lane;                       // pooled pos 0..59
        const float* w1e = ws + OFF_W1E + (size_t)(d * 32) * 81;
        const float* b1e = ws + OFF_B1E + d * 32;
        if (p < 60) {
            float acc0[16], acc1[16];
            #pragma unroll
            for (int i = 0; i < 16; i++) { acc0[i] = 0.f; acc1[i] = 0.f; }
            #pragma unroll
            for (int c = 0; c < 9; c++) {
                float xw[10];
                const float2* src = (const float2*)&xs[(bsub * 9 + c) * 128 + 2 * p];
                #pragma unroll
                for (int j = 0; j < 5; j++) { float2 v = src[j]; xw[2*j] = v.x; xw[2*j+1] = v.y; }
                #pragma unroll
                for (int oo = 0; oo < 16; oo++) {
                    #pragma unroll
                    for (int k = 0; k < 9; k++) {
                        float wv = w1e[(obase + oo) * 81 + c * 9 + k];   // uniform -> s_load
                        acc0[oo] = fmaf(wv, xw[k],     acc0[oo]);
                        acc1[oo] = fmaf(wv, xw[k + 1], acc1[oo]);
                    }
                }
            }
            #pragma unroll
            for (int oo = 0; oo < 16; oo++) {
                float bb = b1e[obase + oo];
                float v = fmaxf(fmaxf(acc0[oo], acc1[oo]) + bb, 0.f);
                h1p[(bsub * 32 + obase + oo) * 60 + p] = v;
            }
        }
    }
    __syncthreads();

    // ---- conv2 + relu + maxpool2 ----
    {
        const int obase = wid * 16;
        const int bsub = lane / 26;               // 0,1 (lanes 52..63 idle)
        const int p = lane % 26;                  // pooled pos 0..25
        const float* w2d = w2 + (size_t)(d * 64) * 288;
        if (lane < 52) {
            float acc0[16], acc1[16];
            #pragma unroll
            for (int i = 0; i < 16; i++) { acc0[i] = 0.f; acc1[i] = 0.f; }
            for (int ic = 0; ic < 32; ic++) {
                float hw[10];
                const float2* src = (const float2*)&h1p[(bsub * 32 + ic) * 60 + 2 * p];
                #pragma unroll
                for (int j = 0; j < 5; j++) { float2 v = src[j]; hw[2*j] = v.x; hw[2*j+1] = v.y; }
                #pragma unroll
                for (int oo = 0; oo < 16; oo++) {
                    #pragma unroll
                    for (int k = 0; k < 9; k++) {
                        float wv = w2d[((obase + oo) * 32 + ic) * 9 + k];  // uniform -> s_load
                        acc0[oo] = fmaf(wv, hw[k],     acc0[oo]);
                        acc1[oo] = fmaf(wv, hw[k + 1], acc1[oo]);
                    }
                }
            }
            #pragma unroll
            for (int oo = 0; oo < 16; oo++) {
                float bb = b2[d * 64 + obase + oo];
                float v = fmaxf(fmaxf(acc0[oo], acc1[oo]) + bb, 0.f);
                h2p[bsub * 1664 + (obase + oo) * 26 + p] = v;
            }
        }
    }
    __syncthreads();

    // ---- fc (1664 -> 12) + relu, write per-domain output ----
    if (t < 192) {
        const int chunk = t & 7;                  // 8 chunks of 208
        const int lb = t >> 3;                    // 0..23
        const int l = lb % 12;
        const int bsub = lb / 12;
        const float4* fw4 = (const float4*)(fcw + ((size_t)(d * 12) + l) * 1664 + chunk * 208);
        const float4* hp4 = (const float4*)(h2p + bsub * 1664 + chunk * 208);
        float s = 0.f;
        #pragma unroll 4
        for (int j = 0; j < 52; j++) {
            float4 a = hp4[j], w = fw4[j];
            s += a.x * w.x + a.y * w.y + a.z * w.z + a.w * w.w;
        }
        s += __shfl_xor(s, 4);
        s += __shfl_xor(s, 2);
        s += __shfl_xor(s, 1);
        if (chunk == 0) {
            float v = fmaxf(s + fcb[d * 12 + l], 0.f);
            pd[((size_t)d * B + b0 + bsub) * 12 + l] = v;
        }
    }
}

// ---------------------------------------------------------------------------
// Kernel 4: out[b,l] = sum_d weights[b,d] * pd[d,b,l]
// ---------------------------------------------------------------------------
__global__ void combine_kernel(const float* __restrict__ weights,
                               const float* __restrict__ pd,
                               float* __restrict__ out) {
    int idx = blockIdx.x * blockDim.x + threadIdx.x;
    if (idx >= B * L) return;
    int b = idx / 12, l = idx % 12;
    float s = 0.f;
    #pragma unroll
    for (int dd = 0; dd < D; dd++)
        s = fmaf(weights[b * 8 + dd], pd[((size_t)dd * B + b) * 12 + l], s);
    out[idx] = s;
}

extern "C" void kernel_launch(void* const* d_in, const int* in_sizes, int n_in,
                              void* d_out, int out_size, void* d_ws, size_t ws_size,
                              hipStream_t stream) {
    const float* x       = (const float*)d_in[0];
    const float* weights = (const float*)d_in[1];
    const float* gamma   = (const float*)d_in[2];
    const float* beta    = (const float*)d_in[3];
    const float* w1      = (const float*)d_in[4];
    const float* b1      = (const float*)d_in[5];
    const float* w2      = (const float*)d_in[6];
    const float* b2      = (const float*)d_in[7];
    const float* fcw     = (const float*)d_in[8];
    const float* fcb     = (const float*)d_in[9];
    float* ws  = (float*)d_ws;
    float* out = (float*)d_out;
    float* pd  = ws + OFF_PD;

    hipMemsetAsync(ws, 0, 18 * sizeof(float), stream);                 // stats bins
    stats_kernel<<<dim3(9 * 64), 256, 0, stream>>>(x, ws);
    fold_kernel<<<1, 256, 0, stream>>>(w1, b1, gamma, beta, ws);
    branch_kernel<<<dim3(B / 2, D), 256, 0, stream>>>(x, w2, b2, fcw, fcb, ws, pd);
    combine_kernel<<<(B * L + 255) / 256, 256, 0, stream>>>(weights, pd, out);
}

// Round 2
// 387.390 us; speedup vs baseline: 3.5681x; 3.5681x over previous
//
#include <hip/hip_runtime.h>

#define D 8
#define L 12
#define C 9
#define W 128
#define B 4096
#define EPS 1e-5f

typedef __attribute__((ext_vector_type(8))) short v8s;   // 8 x bf16
typedef __attribute__((ext_vector_type(4))) float v4f;   // 4 x f32 acc

// Workspace layout (in floats)
#define OFF_STATS 0          // sum[9], sumsq[9]  (zeroed each launch)
#define OFF_B1E   32         // fp32 [D][32] folded conv1 bias
#define OFF_W1T   288        // bf16 [D][32 o][10 tap][16 c]  = 40960 halfs
#define OFF_W2T   20768      // bf16 [D][64 o][9 tap][32 ic]  = 147456 halfs
#define OFF_FCWP  94496      // bf16 [D][12 l][1664 k=p*64+o] = 159744 halfs
#define OFF_PD    174368     // fp32 [D][B][12]

__device__ inline unsigned short f2bf(float f) {
    unsigned u = __builtin_bit_cast(unsigned, f);
    u += 0x7FFFu + ((u >> 16) & 1u);                 // round-nearest-even
    return (unsigned short)(u >> 16);
}
__device__ inline unsigned pk(float a, float b) {
    return (unsigned)f2bf(a) | ((unsigned)f2bf(b) << 16);
}
__device__ inline float dp(float s, unsigned h, unsigned w) {
    float hl = __builtin_bit_cast(float, h << 16);
    float hh = __builtin_bit_cast(float, h & 0xFFFF0000u);
    float wl = __builtin_bit_cast(float, w << 16);
    float wh = __builtin_bit_cast(float, w & 0xFFFF0000u);
    return fmaf(hh, wh, fmaf(hl, wl, s));
}

// ---------------------------------------------------------------------------
// Kernel 1: per-channel sum/sumsq over x (B,C,W) — stats shared by all domains
// ---------------------------------------------------------------------------
__global__ void stats_kernel(const float* __restrict__ x, float* __restrict__ ws) {
    const int c = blockIdx.x % 9;
    const int slice = blockIdx.x / 9;
    const int t = threadIdx.x;
    const int w4 = t & 31, br = t >> 5;
    const float4* x4 = (const float4*)x;
    float s = 0.f, s2 = 0.f;
    for (int b = slice * 8 + br; b < B; b += 64 * 8) {
        float4 v = x4[(size_t)b * 288 + c * 32 + w4];
        s  += v.x + v.y + v.z + v.w;
        s2 += v.x * v.x + v.y * v.y + v.z * v.z + v.w * v.w;
    }
    for (int off = 32; off >= 1; off >>= 1) {
        s  += __shfl_down(s, off);
        s2 += __shfl_down(s2, off);
    }
    if ((t & 63) == 0) {
        atomicAdd(&ws[OFF_STATS + c], s);
        atomicAdd(&ws[OFF_STATS + 9 + c], s2);
    }
}

// ---------------------------------------------------------------------------
// Kernel 2: fold BN into conv1 weights; repack w1/w2/fcw into bf16 MFMA order.
//   w1t[d][o][tap][c16] = w1[d][o][c][tap]*g[c]   (tap 9 and c>=9 zero-padded)
//   b1e[d][o] = b1 + sum w1*bt
//   w2t[d][o][tap][ic]  = w2[d][o][ic][tap]
//   fcwp[d][l][p*64+o]  = fcw[d][l][o*26+p]
// grid = D blocks, 256 threads.
// ---------------------------------------------------------------------------
__global__ void fold_kernel(const float* __restrict__ w1, const float* __restrict__ b1,
                            const float* __restrict__ w2,
                            const float* __restrict__ gamma, const float* __restrict__ beta,
                            const float* __restrict__ fcw, float* __restrict__ ws) {
    const int d = blockIdx.x, t = threadIdx.x;
    __shared__ float g[9], bt[9];
    if (t < 9) {
        const float N = (float)B * (float)W;
        float m  = ws[OFF_STATS + t] / N;
        float vv = ws[OFF_STATS + 9 + t] / N - m * m;
        float inv = rsqrtf(vv + EPS);
        float gg = gamma[d * 9 + t] * inv;
        g[t] = gg; bt[t] = beta[d * 9 + t] - gg * m;
    }
    __syncthreads();
    short* w1t  = (short*)(ws + OFF_W1T);
    short* w2t  = (short*)(ws + OFF_W2T);
    short* fcwp = (short*)(ws + OFF_FCWP);
    if (t < 32) {
        float bias = b1[d * 32 + t];
        short* dst = w1t + (size_t)d * 5120 + t * 160;
        for (int tap = 0; tap < 10; tap++)
            for (int c = 0; c < 16; c++) {
                float v = 0.f;
                if (tap < 9 && c < 9) {
                    float wv = w1[((size_t)(d * 32 + t)) * 81 + c * 9 + tap];
                    v = wv * g[c];
                    bias += wv * bt[c];
                }
                dst[tap * 16 + c] = (short)f2bf(v);
            }
        ws[OFF_B1E + d * 32 + t] = bias;
    }
    for (int i = t; i < 64 * 9 * 32; i += 256) {
        int o = i / 288, r = i % 288, tap = r / 32, ic = r & 31;
        w2t[(size_t)d * 18432 + i] = (short)f2bf(w2[(((size_t)(d * 64 + o)) * 32 + ic) * 9 + tap]);
    }
    for (int i = t; i < 12 * 1664; i += 256) {
        int l = i / 1664, k = i % 1664, p = k >> 6, o = k & 63;
        fcwp[((size_t)(d * 12 + l)) * 1664 + k] = (short)f2bf(fcw[((size_t)(d * 12 + l)) * 1664 + o * 26 + p]);
    }
}

// ---------------------------------------------------------------------------
// Kernel 3: the branch, MFMA version. Block = 8 batch rows x 1 domain,
// 512 threads (8 waves); wave w owns batch row w.
// LDS: ldsA = raw x (fp32) then h1t bf16 [8][72][32];
//      ldsB = xb bf16 [8][144][16] then h2p bf16 [8][26][64]. 72 KB total.
// conv = per-tap GEMMs on mfma_f32_16x16x32_bf16; A=weights (global frags),
// B=activations (contiguous ds_read_b128 frags); pool/bias/relu fused via
// shfl_xor(1) on adjacent n-columns.
// ---------------------------------------------------------------------------
__global__ __launch_bounds__(512, 4)
void branch_kernel(const float* __restrict__ x,
                   const float* __restrict__ b2g,
                   const float* __restrict__ fcb,
                   const float* __restrict__ ws,
                   float* __restrict__ pd) {
    const int t = threadIdx.x;
    const int d = blockIdx.y;
    const int b0 = blockIdx.x * 8;
    const short* w1t  = (const short*)(ws + OFF_W1T);
    const short* w2t  = (const short*)(ws + OFF_W2T);
    const short* fcwp = (const short*)(ws + OFF_FCWP);
    const float* b1e  = ws + OFF_B1E + d * 32;

    __shared__ float ldsA[9216];
    __shared__ float ldsB[9216];
    short* xb  = (short*)ldsB;   // [8][144][16]
    short* h1t = (short*)ldsA;   // [8][72][32]
    short* h2p = (short*)ldsB;   // [8][26][64] (aliases xb, xb dead by then)

    // ---- phase 1: stage raw x (fp32, coalesced) ----
    {
        const float4* xg = (const float4*)(x + (size_t)b0 * 1152);
        float4* xl = (float4*)ldsA;
        for (int i = t; i < 2304; i += 512) xl[i] = xg[i];
    }
    __syncthreads();

    // ---- phase 2: transpose to bf16 [w][c16]; zero pad rows [128,144) ----
    {
        const int bl = t >> 6, wl = t & 63;
        #pragma unroll
        for (int rep = 0; rep < 2; rep++) {
            const int w = wl + rep * 64;
            float v[9];
            #pragma unroll
            for (int c = 0; c < 9; c++) v[c] = ldsA[bl * 1152 + c * 128 + w];
            uint4 lo, hi;
            lo.x = pk(v[0], v[1]); lo.y = pk(v[2], v[3]);
            lo.z = pk(v[4], v[5]); lo.w = pk(v[6], v[7]);
            hi.x = (unsigned)(unsigned short)f2bf(v[8]); hi.y = 0; hi.z = 0; hi.w = 0;
            uint4* dst = (uint4*)&xb[(bl * 144 + w) * 16];
            dst[0] = lo; dst[1] = hi;
        }
        if (wl < 16) {
            uint4 z; z.x = z.y = z.z = z.w = 0;
            uint4* dst = (uint4*)&xb[(bl * 144 + 128 + wl) * 16];
            dst[0] = z; dst[1] = z;
        }
    }
    __syncthreads();

    // ---- phase 3: conv1 (M=32, K=2taps x 16c, 5 ksteps) + pool -> h1t ----
    {
        const int wv = t >> 6, lane = t & 63;
        const int n = lane & 15, quad = lane >> 4;
        const int qh = quad >> 1, ql = quad & 1;
        v4f acc[2][8];
        #pragma unroll
        for (int mt = 0; mt < 2; mt++)
            #pragma unroll
            for (int nt = 0; nt < 8; nt++) { v4f z = {0.f,0.f,0.f,0.f}; acc[mt][nt] = z; }
        const short* w1p = w1t + (size_t)d * 5120;
        #pragma unroll
        for (int s = 0; s < 5; s++) {
            v8s A0 = *(const v8s*)&w1p[n * 160 + (2 * s + qh) * 16 + ql * 8];
            v8s A1 = *(const v8s*)&w1p[(16 + n) * 160 + (2 * s + qh) * 16 + ql * 8];
            #pragma unroll
            for (int nt = 0; nt < 8; nt++) {
                const int row = nt * 16 + n + 2 * s + qh;
                v8s Bf = *(const v8s*)&xb[(wv * 144 + row) * 16 + ql * 8];
                acc[0][nt] = __builtin_amdgcn_mfma_f32_16x16x32_bf16(A0, Bf, acc[0][nt], 0, 0, 0);
                acc[1][nt] = __builtin_amdgcn_mfma_f32_16x16x32_bf16(A1, Bf, acc[1][nt], 0, 0, 0);
            }
        }
        #pragma unroll
        for (int mt = 0; mt < 2; mt++) {
            float bias[4];
            #pragma unroll
            for (int r = 0; r < 4; r++) bias[r] = b1e[mt * 16 + quad * 4 + r];
            #pragma unroll
            for (int nt = 0; nt < 8; nt++) {
                const int praw = nt * 16 + n;
                float hv[4];
                #pragma unroll
                for (int r = 0; r < 4; r++) {
                    float v0 = acc[mt][nt][r] + bias[r];
                    float v1 = __shfl_xor(v0, 1);
                    hv[r] = fmaxf(fmaxf(v0, v1), 0.f);
                }
                if (!(praw & 1) && praw < 120) {
                    uint2 pkv; pkv.x = pk(hv[0], hv[1]); pkv.y = pk(hv[2], hv[3]);
                    *(uint2*)&h1t[(wv * 72 + (praw >> 1)) * 32 + mt * 16 + quad * 4] = pkv;
                }
            }
        }
    }
    __syncthreads();

    // ---- phase 4: conv2 (M=64, K=32 ic, 9 taps) + pool -> h2p ----
    {
        const int wv = t >> 6, lane = t & 63;
        const int n = lane & 15, quad = lane >> 4;
        v4f acc[4][4];
        #pragma unroll
        for (int mt = 0; mt < 4; mt++)
            #pragma unroll
            for (int nt = 0; nt < 4; nt++) { v4f z = {0.f,0.f,0.f,0.f}; acc[mt][nt] = z; }
        const short* w2p = w2t + (size_t)d * 18432;
        for (int tap = 0; tap < 9; tap++) {
            v8s A[4];
            #pragma unroll
            for (int mt = 0; mt < 4; mt++)
                A[mt] = *(const v8s*)&w2p[(mt * 16 + n) * 288 + tap * 32 + quad * 8];
            #pragma unroll
            for (int nt = 0; nt < 4; nt++) {
                const int row = nt * 16 + n + tap;
                v8s Bf = *(const v8s*)&h1t[(wv * 72 + row) * 32 + quad * 8];
                #pragma unroll
                for (int mt = 0; mt < 4; mt++)
                    acc[mt][nt] = __builtin_amdgcn_mfma_f32_16x16x32_bf16(A[mt], Bf, acc[mt][nt], 0, 0, 0);
            }
        }
        #pragma unroll
        for (int mt = 0; mt < 4; mt++) {
            float bias[4];
            #pragma unroll
            for (int r = 0; r < 4; r++) bias[r] = b2g[d * 64 + mt * 16 + quad * 4 + r];
            #pragma unroll
            for (int nt = 0; nt < 4; nt++) {
                const int praw = nt * 16 + n;
                float hv[4];
                #pragma unroll
                for (int r = 0; r < 4; r++) {
                    float v0 = acc[mt][nt][r] + bias[r];
                    float v1 = __shfl_xor(v0, 1);
                    hv[r] = fmaxf(fmaxf(v0, v1), 0.f);
                }
                if (!(praw & 1) && praw < 52) {
                    uint2 pkv; pkv.x = pk(hv[0], hv[1]); pkv.y = pk(hv[2], hv[3]);
                    *(uint2*)&h2p[(wv * 26 + (praw >> 1)) * 64 + mt * 16 + quad * 4] = pkv;
                }
            }
        }
    }
    __syncthreads();

    // ---- phase 5: fc (1664 -> 12) + relu -> pd ----
    if (t < 384) {
        const int b_ = t / 48, rem = t % 48;
        const int l = rem >> 2, ch = rem & 3;
        const short* wr = fcwp + ((size_t)(d * 12) + l) * 1664 + ch * 416;
        const short* hr = h2p + b_ * 1664 + ch * 416;
        float s = 0.f;
        #pragma unroll 4
        for (int i = 0; i < 52; i++) {
            uint4 hu = *(const uint4*)&hr[i * 8];
            uint4 wu = *(const uint4*)&wr[i * 8];
            s = dp(s, hu.x, wu.x); s = dp(s, hu.y, wu.y);
            s = dp(s, hu.z, wu.z); s = dp(s, hu.w, wu.w);
        }
        s += __shfl_xor(s, 1);
        s += __shfl_xor(s, 2);
        if (ch == 0)
            pd[((size_t)d * B + b0 + b_) * 12 + l] = fmaxf(s + fcb[d * 12 + l], 0.f);
    }
}

// ---------------------------------------------------------------------------
// Kernel 4: out[b,l] = sum_d weights[b,d] * pd[d,b,l]
// ---------------------------------------------------------------------------
__global__ void combine_kernel(const float* __restrict__ weights,
                               const float* __restrict__ pd,
                               float* __restrict__ out) {
    int idx = blockIdx.x * blockDim.x + threadIdx.x;
    if (idx >= B * L) return;
    int b = idx / 12, l = idx % 12;
    float s = 0.f;
    #pragma unroll
    for (int dd = 0; dd < D; dd++)
        s = fmaf(weights[b * 8 + dd], pd[((size_t)dd * B + b) * 12 + l], s);
    out[idx] = s;
}

extern "C" void kernel_launch(void* const* d_in, const int* in_sizes, int n_in,
                              void* d_out, int out_size, void* d_ws, size_t ws_size,
                              hipStream_t stream) {
    const float* x       = (const float*)d_in[0];
    const float* weights = (const float*)d_in[1];
    const float* gamma   = (const float*)d_in[2];
    const float* beta    = (const float*)d_in[3];
    const float* w1      = (const float*)d_in[4];
    const float* b1      = (const float*)d_in[5];
    const float* w2      = (const float*)d_in[6];
    const float* b2      = (const float*)d_in[7];
    const float* fcw     = (const float*)d_in[8];
    const float* fcb     = (const float*)d_in[9];
    float* ws  = (float*)d_ws;
    float* out = (float*)d_out;
    float* pd  = ws + OFF_PD;

    hipMemsetAsync(ws, 0, 18 * sizeof(float), stream);
    stats_kernel<<<dim3(9 * 64), 256, 0, stream>>>(x, ws);
    fold_kernel<<<dim3(D), 256, 0, stream>>>(w1, b1, w2, gamma, beta, fcw, ws);
    branch_kernel<<<dim3(B / 8, D), 512, 0, stream>>>(x, b2, fcb, ws, pd);
    combine_kernel<<<(B * L + 255) / 256, 256, 0, stream>>>(weights, pd, out);
}

// Round 3
// 317.602 us; speedup vs baseline: 4.3522x; 1.2197x over previous
//
#include <hip/hip_runtime.h>

#define D 8
#define L 12
#define C 9
#define W 128
#define B 4096
#define EPS 1e-5f

typedef __attribute__((ext_vector_type(8))) short v8s;   // 8 x bf16
typedef __attribute__((ext_vector_type(4))) float v4f;   // 4 x f32 acc

// Workspace layout (in floats) — identical footprint to R2 (2.16 MB)
#define OFF_STATS 0          // sum[9], sumsq[9]  (zeroed each launch)
#define OFF_B1E   32         // fp32 [D][32] folded conv1 bias
#define OFF_W1T   288        // bf16 [D][32 o][10 tap][16 c]  = 40960 halfs
#define OFF_W2T   20768      // bf16 [D][64 o][9 tap][32 ic]  = 147456 halfs
#define OFF_FCWP  94496      // bf16 [D][12 l][1664 k=p*64+o] = 159744 halfs
#define OFF_PD    174368     // fp32 [D][B][12]

__device__ inline unsigned short f2bf(float f) {
    unsigned u = __builtin_bit_cast(unsigned, f);
    u += 0x7FFFu + ((u >> 16) & 1u);                 // round-nearest-even
    return (unsigned short)(u >> 16);
}
__device__ inline unsigned pk(float a, float b) {
    return (unsigned)f2bf(a) | ((unsigned)f2bf(b) << 16);
}

// ---------------------------------------------------------------------------
// Kernel 1: per-channel sum/sumsq over x (B,C,W) — stats shared by all domains
// ---------------------------------------------------------------------------
__global__ void stats_kernel(const float* __restrict__ x, float* __restrict__ ws) {
    const int c = blockIdx.x % 9;
    const int slice = blockIdx.x / 9;
    const int t = threadIdx.x;
    const int w4 = t & 31, br = t >> 5;
    const float4* x4 = (const float4*)x;
    float s = 0.f, s2 = 0.f;
    for (int b = slice * 8 + br; b < B; b += 64 * 8) {
        float4 v = x4[(size_t)b * 288 + c * 32 + w4];
        s  += v.x + v.y + v.z + v.w;
        s2 += v.x * v.x + v.y * v.y + v.z * v.z + v.w * v.w;
    }
    for (int off = 32; off >= 1; off >>= 1) {
        s  += __shfl_down(s, off);
        s2 += __shfl_down(s2, off);
    }
    if ((t & 63) == 0) {
        atomicAdd(&ws[OFF_STATS + c], s);
        atomicAdd(&ws[OFF_STATS + 9 + c], s2);
    }
}

// ---------------------------------------------------------------------------
// Kernel 2: fold BN into conv1 weights; repack w1/w2/fcw to bf16 MFMA order.
// grid = (6, D): bx0 = w1 fold+bias, bx1-2 = w2t, bx3-5 = fcwp.
// ---------------------------------------------------------------------------
__global__ void fold_kernel(const float* __restrict__ w1, const float* __restrict__ b1,
                            const float* __restrict__ w2,
                            const float* __restrict__ gamma, const float* __restrict__ beta,
                            const float* __restrict__ fcw, float* __restrict__ ws) {
    const int d = blockIdx.y, part = blockIdx.x, t = threadIdx.x;
    short* w1t  = (short*)(ws + OFF_W1T);
    short* w2t  = (short*)(ws + OFF_W2T);
    short* fcwp = (short*)(ws + OFF_FCWP);
    if (part == 0) {
        __shared__ float g[9], bt[9];
        if (t < 9) {
            const float N = (float)B * (float)W;
            float m  = ws[OFF_STATS + t] / N;
            float vv = ws[OFF_STATS + 9 + t] / N - m * m;
            float inv = rsqrtf(vv + EPS);
            float gg = gamma[d * 9 + t] * inv;
            g[t] = gg; bt[t] = beta[d * 9 + t] - gg * m;
        }
        __syncthreads();
        if (t < 32) {
            float bias = b1[d * 32 + t];
            short* dst = w1t + (size_t)d * 5120 + t * 160;
            for (int tap = 0; tap < 10; tap++)
                for (int c = 0; c < 16; c++) {
                    float v = 0.f;
                    if (tap < 9 && c < 9) {
                        float wv = w1[((size_t)(d * 32 + t)) * 81 + c * 9 + tap];
                        v = wv * g[c];
                        bias += wv * bt[c];
                    }
                    dst[tap * 16 + c] = (short)f2bf(v);
                }
            ws[OFF_B1E + d * 32 + t] = bias;
        }
    } else if (part <= 2) {
        for (int i = (part - 1) * 256 + t; i < 64 * 9 * 32; i += 512) {
            int o = i / 288, r = i % 288, tap = r / 32, ic = r & 31;
            w2t[(size_t)d * 18432 + i] =
                (short)f2bf(w2[(((size_t)(d * 64 + o)) * 32 + ic) * 9 + tap]);
        }
    } else {
        for (int i = (part - 3) * 256 + t; i < 12 * 1664; i += 768) {
            int l = i / 1664, k = i % 1664, p = k >> 6, o = k & 63;
            fcwp[((size_t)d * 12) * 1664 + i] =
                (short)f2bf(fcw[((size_t)(d * 12 + l)) * 1664 + o * 26 + p]);
        }
    }
}

// ---------------------------------------------------------------------------
// Kernel 3: the branch. Block = 8 batch rows x 1 domain, 512 threads (8 waves),
// wave wv owns batch row wv. All LDS B-fragment layouts are quad-planar:
// 8 consecutive lanes read 8 consecutive 16B rows = 128B contiguous -> no
// bank conflicts. FC is MFMA (K split over waves) + fp32 LDS reduction.
//   ldsB: xb [8 b][2 ql][144 row][8]  -> h2p [8 b][1672 k]   (aliased)
//   ldsA: h1t [8 b][4 quad][72 row][8] -> red [8][64][4] f32 (aliased)
// ---------------------------------------------------------------------------
__global__ __launch_bounds__(512, 4)
void branch_kernel(const float* __restrict__ x,
                   const float* __restrict__ b2g,
                   const float* __restrict__ fcb,
                   const float* __restrict__ ws,
                   float* __restrict__ pd) {
    const int t = threadIdx.x;
    const int lane = t & 63;
    const int wv = __builtin_amdgcn_readfirstlane(t >> 6);
    const int d = blockIdx.y;
    const int b0 = blockIdx.x * 8;
    const short* w1t  = (const short*)(ws + OFF_W1T);
    const short* w2t  = (const short*)(ws + OFF_W2T);
    const short* fcwp = (const short*)(ws + OFF_FCWP);
    const float* b1e  = ws + OFF_B1E + d * 32;

    __shared__ __align__(16) short ldsA[18432];   // 36 KB
    __shared__ __align__(16) short ldsB[18432];   // 36 KB
    short* xb  = ldsB;                 // [b*2+ql][144][8]
    short* h1t = ldsA;                 // [b*4+quad][72][8]
    short* h2p = ldsB;                 // [b][1672]
    float* red = (float*)ldsA;         // [8][64][4]

    // ---- phase 1: load x transposed straight from global (lanes = w: coalesced) ----
    {
        const float* xrow = x + (size_t)(b0 + wv) * 1152;
        #pragma unroll
        for (int rep = 0; rep < 2; rep++) {
            const int w = lane + rep * 64;
            float v[9];
            #pragma unroll
            for (int c = 0; c < 9; c++) v[c] = xrow[c * 128 + w];
            uint4 lo, hi;
            lo.x = pk(v[0], v[1]); lo.y = pk(v[2], v[3]);
            lo.z = pk(v[4], v[5]); lo.w = pk(v[6], v[7]);
            hi.x = (unsigned)(unsigned short)f2bf(v[8]); hi.y = 0; hi.z = 0; hi.w = 0;
            *(uint4*)&xb[((wv * 2 + 0) * 144 + w) * 8] = lo;
            *(uint4*)&xb[((wv * 2 + 1) * 144 + w) * 8] = hi;
        }
        if (lane < 16) {   // zero pad rows 128..143, both planes
            uint4 z; z.x = z.y = z.z = z.w = 0;
            *(uint4*)&xb[((wv * 2 + 0) * 144 + 128 + lane) * 8] = z;
            *(uint4*)&xb[((wv * 2 + 1) * 144 + 128 + lane) * 8] = z;
        }
    }
    __syncthreads();

    // ---- phase 2: conv1 (M=32, K=5 steps of 2tap x 16c) + pool -> h1t ----
    {
        const int n = lane & 15, quad = lane >> 4;
        const int qh = quad >> 1, ql = quad & 1;
        v4f acc[2][8];
        #pragma unroll
        for (int mt = 0; mt < 2; mt++)
            #pragma unroll
            for (int nt = 0; nt < 8; nt++) { v4f z = {0.f,0.f,0.f,0.f}; acc[mt][nt] = z; }
        const short* w1p = w1t + (size_t)d * 5120;
        #pragma unroll
        for (int s = 0; s < 5; s++) {
            v8s A0 = *(const v8s*)&w1p[n * 160 + (2 * s + qh) * 16 + ql * 8];
            v8s A1 = *(const v8s*)&w1p[(16 + n) * 160 + (2 * s + qh) * 16 + ql * 8];
            #pragma unroll
            for (int nt = 0; nt < 8; nt++) {
                const int row = nt * 16 + n + 2 * s + qh;
                v8s Bf = *(const v8s*)&xb[((wv * 2 + ql) * 144 + row) * 8];
                acc[0][nt] = __builtin_amdgcn_mfma_f32_16x16x32_bf16(A0, Bf, acc[0][nt], 0, 0, 0);
                acc[1][nt] = __builtin_amdgcn_mfma_f32_16x16x32_bf16(A1, Bf, acc[1][nt], 0, 0, 0);
            }
        }
        #pragma unroll
        for (int mt = 0; mt < 2; mt++) {
            float bias[4];
            #pragma unroll
            for (int r = 0; r < 4; r++) bias[r] = b1e[mt * 16 + quad * 4 + r];
            const int qc = mt * 2 + (quad >> 1);        // ic-chunk = oc>>3
            const int off = (quad & 1) * 4;             // oc&7 base
            #pragma unroll
            for (int nt = 0; nt < 8; nt++) {
                const int praw = nt * 16 + n;
                float hv[4];
                #pragma unroll
                for (int r = 0; r < 4; r++) {
                    float v0 = acc[mt][nt][r] + bias[r];
                    float v1 = __shfl_xor(v0, 1);
                    hv[r] = fmaxf(fmaxf(v0, v1), 0.f);
                }
                if (!(praw & 1) && praw < 120) {
                    uint2 pkv; pkv.x = pk(hv[0], hv[1]); pkv.y = pk(hv[2], hv[3]);
                    *(uint2*)&h1t[((wv * 4 + qc) * 72 + (praw >> 1)) * 8 + off] = pkv;
                }
            }
        }
    }
    __syncthreads();

    // ---- phase 3: conv2 (M=64, K=9 taps x 32 ic) + pool -> h2p [b][p*64+o] ----
    {
        const int n = lane & 15, quad = lane >> 4;
        v4f acc[4][4];
        #pragma unroll
        for (int mt = 0; mt < 4; mt++)
            #pragma unroll
            for (int nt = 0; nt < 4; nt++) { v4f z = {0.f,0.f,0.f,0.f}; acc[mt][nt] = z; }
        const short* w2p = w2t + (size_t)d * 18432;
        for (int tap = 0; tap < 9; tap++) {
            v8s A[4];
            #pragma unroll
            for (int mt = 0; mt < 4; mt++)
                A[mt] = *(const v8s*)&w2p[(mt * 16 + n) * 288 + tap * 32 + quad * 8];
            #pragma unroll
            for (int nt = 0; nt < 4; nt++) {
                const int row = nt * 16 + n + tap;
                v8s Bf = *(const v8s*)&h1t[((wv * 4 + quad) * 72 + row) * 8];
                #pragma unroll
                for (int mt = 0; mt < 4; mt++)
                    acc[mt][nt] = __builtin_amdgcn_mfma_f32_16x16x32_bf16(A[mt], Bf, acc[mt][nt], 0, 0, 0);
            }
        }
        #pragma unroll
        for (int mt = 0; mt < 4; mt++) {
            float bias[4];
            #pragma unroll
            for (int r = 0; r < 4; r++) bias[r] = b2g[d * 64 + mt * 16 + quad * 4 + r];
            #pragma unroll
            for (int nt = 0; nt < 4; nt++) {
                const int praw = nt * 16 + n;
                float hv[4];
                #pragma unroll
                for (int r = 0; r < 4; r++) {
                    float v0 = acc[mt][nt][r] + bias[r];
                    float v1 = __shfl_xor(v0, 1);
                    hv[r] = fmaxf(fmaxf(v0, v1), 0.f);
                }
                if (!(praw & 1) && praw < 52) {
                    uint2 pkv; pkv.x = pk(hv[0], hv[1]); pkv.y = pk(hv[2], hv[3]);
                    *(uint2*)&h2p[wv * 1672 + (praw >> 1) * 64 + mt * 16 + quad * 4] = pkv;
                }
            }
        }
    }
    __syncthreads();

    // ---- phase 4: fc via MFMA. M=16(l,12 used), N=16(b,8 used), K=1664.
    //      52 ksteps strided over 8 waves; fp32 partials reduced via LDS. ----
    {
        const int n = lane & 15, quad = lane >> 4;
        int lrow = (n < 12) ? n : 0;                  // pad l rows by duplication
        const short* fr = fcwp + ((size_t)d * 12) * 1664;
        v4f acc = {0.f, 0.f, 0.f, 0.f};
        for (int ks = wv; ks < 52; ks += 8) {
            v8s A  = *(const v8s*)&fr[lrow * 1664 + ks * 32 + quad * 8];
            v8s Bf = *(const v8s*)&h2p[(n & 7) * 1672 + ks * 32 + quad * 8];
            acc = __builtin_amdgcn_mfma_f32_16x16x32_bf16(A, Bf, acc, 0, 0, 0);
        }
        __syncthreads();   // h1t (ldsA) dead -> red may overwrite
        *(float4*)&red[(wv * 64 + lane) * 4] = *(float4*)&acc;
    }
    __syncthreads();
    if (t < 64) {
        const int n = lane & 15, quad = lane >> 4;
        float sum[4] = {0.f, 0.f, 0.f, 0.f};
        #pragma unroll
        for (int w = 0; w < 8; w++) {
            float4 v = *(const float4*)&red[(w * 64 + lane) * 4];
            sum[0] += v.x; sum[1] += v.y; sum[2] += v.z; sum[3] += v.w;
        }
        if (n < 8) {
            #pragma unroll
            for (int r = 0; r < 4; r++) {
                const int l = quad * 4 + r;
                if (l < 12)
                    pd[((size_t)d * B + b0 + n) * 12 + l] =
                        fmaxf(sum[r] + fcb[d * 12 + l], 0.f);
            }
        }
    }
}

// ---------------------------------------------------------------------------
// Kernel 4: out[b,l] = sum_d weights[b,d] * pd[d,b,l]
// ---------------------------------------------------------------------------
__global__ void combine_kernel(const float* __restrict__ weights,
                               const float* __restrict__ pd,
                               float* __restrict__ out) {
    int idx = blockIdx.x * blockDim.x + threadIdx.x;
    if (idx >= B * L) return;
    int b = idx / 12, l = idx % 12;
    float s = 0.f;
    #pragma unroll
    for (int dd = 0; dd < D; dd++)
        s = fmaf(weights[b * 8 + dd], pd[((size_t)dd * B + b) * 12 + l], s);
    out[idx] = s;
}

extern "C" void kernel_launch(void* const* d_in, const int* in_sizes, int n_in,
                              void* d_out, int out_size, void* d_ws, size_t ws_size,
                              hipStream_t stream) {
    const float* x       = (const float*)d_in[0];
    const float* weights = (const float*)d_in[1];
    const float* gamma   = (const float*)d_in[2];
    const float* beta    = (const float*)d_in[3];
    const float* w1      = (const float*)d_in[4];
    const float* b1      = (const float*)d_in[5];
    const float* w2      = (const float*)d_in[6];
    const float* b2      = (const float*)d_in[7];
    const float* fcw     = (const float*)d_in[8];
    const float* fcb     = (const float*)d_in[9];
    float* ws  = (float*)d_ws;
    float* out = (float*)d_out;
    float* pd  = ws + OFF_PD;

    hipMemsetAsync(ws, 0, 18 * sizeof(float), stream);
    stats_kernel<<<dim3(9 * 64), 256, 0, stream>>>(x, ws);
    fold_kernel<<<dim3(6, D), 256, 0, stream>>>(w1, b1, w2, gamma, beta, fcw, ws);
    branch_kernel<<<dim3(B / 8, D), 512, 0, stream>>>(x, b2, fcb, ws, pd);
    combine_kernel<<<(B * L + 255) / 256, 256, 0, stream>>>(weights, pd, out);
}

// Round 5
// 307.543 us; speedup vs baseline: 4.4945x; 1.0327x over previous
//
#include <hip/hip_runtime.h>
#include <hip/hip_bf16.h>

#define D 8
#define L 12
#define C 9
#define W 128
#define B 4096
#define EPS 1e-5f

typedef __attribute__((ext_vector_type(8))) short v8s;   // 8 x bf16
typedef __attribute__((ext_vector_type(4))) float v4f;   // 4 x f32 acc

// Workspace layout (in floats)
#define OFF_STATS 0          // sum[9], sumsq[9]  (zeroed each launch)
#define OFF_B1E   32         // fp32 [D][32] folded conv1 bias
#define OFF_W1T   288        // bf16 [D][32 o][10 tap][16 c]  = 40960 halfs
#define OFF_W2T   20768      // bf16 [D][64 o][9 tap][32 ic]  = 147456 halfs
#define OFF_FCWP  94496      // bf16 [D][12 l][1664 k=p*64+o] = 159744 halfs

__device__ inline unsigned short f2bf(float f) {
    unsigned u = __builtin_bit_cast(unsigned, f);
    u += 0x7FFFu + ((u >> 16) & 1u);                 // round-nearest-even
    return (unsigned short)(u >> 16);
}
__device__ inline unsigned pk2(float a, float b) {
    float2 f2; f2.x = a; f2.y = b;
    __hip_bfloat162 h = __float22bfloat162_rn(f2);   // v_cvt_pk_bf16_f32 on gfx950
    unsigned u; __builtin_memcpy(&u, &h, 4);
    return u;
}

// ---------------------------------------------------------------------------
// Kernel 1: stats (blocks 0..575) + w2t/fcwp bf16 repack (blocks 576..615).
// Repack is independent of stats, so it rides in the same dispatch.
// ---------------------------------------------------------------------------
__global__ void stats_repack_kernel(const float* __restrict__ x,
                                    const float* __restrict__ w2,
                                    const float* __restrict__ fcw,
                                    float* __restrict__ ws) {
    const int t = threadIdx.x;
    if (blockIdx.x < 576) {
        const int c = blockIdx.x % 9;
        const int slice = blockIdx.x / 9;
        const int w4 = t & 31, br = t >> 5;
        const float4* x4 = (const float4*)x;
        float s = 0.f, s2 = 0.f;
        for (int b = slice * 8 + br; b < B; b += 64 * 8) {
            float4 v = x4[(size_t)b * 288 + c * 32 + w4];
            s  += v.x + v.y + v.z + v.w;
            s2 += v.x * v.x + v.y * v.y + v.z * v.z + v.w * v.w;
        }
        for (int off = 32; off >= 1; off >>= 1) {
            s  += __shfl_down(s, off);
            s2 += __shfl_down(s2, off);
        }
        if ((t & 63) == 0) {
            atomicAdd(&ws[OFF_STATS + c], s);
            atomicAdd(&ws[OFF_STATS + 9 + c], s2);
        }
    } else {
        const int i0 = blockIdx.x - 576;
        const int d = i0 / 5, part = i0 % 5;
        short* w2t  = (short*)(ws + OFF_W2T);
        short* fcwp = (short*)(ws + OFF_FCWP);
        if (part < 2) {
            for (int i = part * 256 + t; i < 64 * 9 * 32; i += 512) {
                int o = i / 288, r = i % 288, tap = r / 32, ic = r & 31;
                w2t[(size_t)d * 18432 + i] =
                    (short)f2bf(w2[(((size_t)(d * 64 + o)) * 32 + ic) * 9 + tap]);
            }
        } else {
            for (int i = (part - 2) * 256 + t; i < 12 * 1664; i += 768) {
                int l = i / 1664, k = i % 1664, p = k >> 6, o = k & 63;
                fcwp[((size_t)d * 12) * 1664 + i] =
                    (short)f2bf(fcw[((size_t)(d * 12 + l)) * 1664 + o * 26 + p]);
            }
        }
    }
}

// ---------------------------------------------------------------------------
// Kernel 2: fold BN into conv1 weights + bias. grid = D, 256 threads:
// o = t>>3 (32 outputs), sub = t&7 splits the (tap,c) work; bias shuffle-
// reduced over the 8 sub lanes. ~20 independent loads/thread: latency-hidden.
// ---------------------------------------------------------------------------
__global__ void fold1_kernel(const float* __restrict__ w1, const float* __restrict__ b1,
                             const float* __restrict__ gamma, const float* __restrict__ beta,
                             float* __restrict__ ws) {
    const int d = blockIdx.x, t = threadIdx.x;
    __shared__ float g[9], bt[9];
    if (t < 9) {
        const float N = (float)B * (float)W;
        float m  = ws[OFF_STATS + t] / N;
        float vv = ws[OFF_STATS + 9 + t] / N - m * m;
        float inv = rsqrtf(vv + EPS);
        float gg = gamma[d * 9 + t] * inv;
        g[t] = gg; bt[t] = beta[d * 9 + t] - gg * m;
    }
    __syncthreads();
    const int o = t >> 3, sub = t & 7;
    short* w1t = (short*)(ws + OFF_W1T);
    short* dst = w1t + (size_t)d * 5120 + o * 160;
    const float* src = w1 + ((size_t)(d * 32 + o)) * 81;
    float bias_part = 0.f;
    for (int tap = sub; tap < 10; tap += 8) {
        for (int c = 0; c < 16; c++) {
            float v = 0.f;
            if (tap < 9 && c < 9) {
                float wv = src[c * 9 + tap];
                v = wv * g[c];
                bias_part += wv * bt[c];
            }
            dst[tap * 16 + c] = (short)f2bf(v);
        }
    }
    bias_part += __shfl_xor(bias_part, 1);
    bias_part += __shfl_xor(bias_part, 2);
    bias_part += __shfl_xor(bias_part, 4);
    if (sub == 0) ws[OFF_B1E + d * 32 + o] = b1[d * 32 + o] + bias_part;
}

// ---------------------------------------------------------------------------
// Kernel 3: the branch. Block = 8 batch rows x 1 domain, 512 threads (8 waves),
// wave wv owns batch row wv. Quad-planar LDS layouts keep all fragment
// reads/writes at <=2-way bank aliasing; h2p uses an XOR chunk swizzle
// (g' = g ^ (p&7)) so phase-3 writes (raw-pos stride 128B) spread over all
// bank groups. FC via MFMA (K strided over waves) + fp32 LDS reduce; the
// d-combine (einsum) is fused via atomicAdd into pre-zeroed d_out.
// ---------------------------------------------------------------------------
__global__ __launch_bounds__(512, 4)
void branch_kernel(const float* __restrict__ x,
                   const float* __restrict__ b2g,
                   const float* __restrict__ fcb,
                   const float* __restrict__ wts,
                   const float* __restrict__ ws,
                   float* __restrict__ out) {
    const int t = threadIdx.x;
    const int lane = t & 63;
    const int wv = __builtin_amdgcn_readfirstlane(t >> 6);
    const int d = blockIdx.y;
    const int b0 = blockIdx.x * 8;
    const short* w1t  = (const short*)(ws + OFF_W1T);
    const short* w2t  = (const short*)(ws + OFF_W2T);
    const short* fcwp = (const short*)(ws + OFF_FCWP);
    const float* b1e  = ws + OFF_B1E + d * 32;

    __shared__ __align__(16) short ldsA[18432];   // 36 KB
    __shared__ __align__(16) short ldsB[18432];   // 36 KB
    short* xb  = ldsB;                 // [b*2+ql][144][8]
    short* h1t = ldsA;                 // [b*4+quad][72][8]
    short* h2p = ldsB;                 // [b][1672], XOR-swizzled 16B chunks
    float* red = (float*)ldsA;         // [8][64][4]

    // ---- phase 1: load x transposed straight from global (lanes = w) ----
    {
        const float* xrow = x + (size_t)(b0 + wv) * 1152;
        #pragma unroll
        for (int rep = 0; rep < 2; rep++) {
            const int w = lane + rep * 64;
            float v[9];
            #pragma unroll
            for (int c = 0; c < 9; c++) v[c] = xrow[c * 128 + w];
            uint4 lo, hi;
            lo.x = pk2(v[0], v[1]); lo.y = pk2(v[2], v[3]);
            lo.z = pk2(v[4], v[5]); lo.w = pk2(v[6], v[7]);
            hi.x = (unsigned)(unsigned short)f2bf(v[8]); hi.y = 0; hi.z = 0; hi.w = 0;
            *(uint4*)&xb[((wv * 2 + 0) * 144 + w) * 8] = lo;
            *(uint4*)&xb[((wv * 2 + 1) * 144 + w) * 8] = hi;
        }
        if (lane < 16) {   // zero pad rows 128..143, both planes
            uint4 z; z.x = z.y = z.z = z.w = 0;
            *(uint4*)&xb[((wv * 2 + 0) * 144 + 128 + lane) * 8] = z;
            *(uint4*)&xb[((wv * 2 + 1) * 144 + 128 + lane) * 8] = z;
        }
    }
    __syncthreads();

    // ---- phase 2: conv1 (M=32, K=5 steps of 2tap x 16c) + pool -> h1t ----
    {
        const int n = lane & 15, quad = lane >> 4;
        const int qh = quad >> 1, ql = quad & 1;
        v4f acc[2][8];
        #pragma unroll
        for (int mt = 0; mt < 2; mt++)
            #pragma unroll
            for (int nt = 0; nt < 8; nt++) { v4f z = {0.f,0.f,0.f,0.f}; acc[mt][nt] = z; }
        const short* w1p = w1t + (size_t)d * 5120;
        #pragma unroll
        for (int s = 0; s < 5; s++) {
            v8s A0 = *(const v8s*)&w1p[n * 160 + (2 * s + qh) * 16 + ql * 8];
            v8s A1 = *(const v8s*)&w1p[(16 + n) * 160 + (2 * s + qh) * 16 + ql * 8];
            #pragma unroll
            for (int nt = 0; nt < 8; nt++) {
                const int row = nt * 16 + n + 2 * s + qh;
                v8s Bf = *(const v8s*)&xb[((wv * 2 + ql) * 144 + row) * 8];
                acc[0][nt] = __builtin_amdgcn_mfma_f32_16x16x32_bf16(A0, Bf, acc[0][nt], 0, 0, 0);
                acc[1][nt] = __builtin_amdgcn_mfma_f32_16x16x32_bf16(A1, Bf, acc[1][nt], 0, 0, 0);
            }
        }
        #pragma unroll
        for (int mt = 0; mt < 2; mt++) {
            float bias[4];
            #pragma unroll
            for (int r = 0; r < 4; r++) bias[r] = b1e[mt * 16 + quad * 4 + r];
            const int qc = mt * 2 + (quad >> 1);        // ic-chunk = oc>>3
            const int off = (quad & 1) * 4;             // oc&7 base
            #pragma unroll
            for (int nt = 0; nt < 8; nt++) {
                const int praw = nt * 16 + n;
                float hv[4];
                #pragma unroll
                for (int r = 0; r < 4; r++) {
                    float v0 = acc[mt][nt][r] + bias[r];
                    float v1 = __shfl_xor(v0, 1);
                    hv[r] = fmaxf(fmaxf(v0, v1), 0.f);
                }
                if (!(praw & 1) && praw < 120) {
                    uint2 pkv; pkv.x = pk2(hv[0], hv[1]); pkv.y = pk2(hv[2], hv[3]);
                    *(uint2*)&h1t[((wv * 4 + qc) * 72 + (praw >> 1)) * 8 + off] = pkv;
                }
            }
        }
    }
    __syncthreads();

    // ---- phase 3: conv2 (M=64, K=9 taps x 32 ic) + pool -> h2p (swizzled) ----
    {
        const int n = lane & 15, quad = lane >> 4;
        v4f acc[4][4];
        #pragma unroll
        for (int mt = 0; mt < 4; mt++)
            #pragma unroll
            for (int nt = 0; nt < 4; nt++) { v4f z = {0.f,0.f,0.f,0.f}; acc[mt][nt] = z; }
        const short* w2p = w2t + (size_t)d * 18432;
        for (int tap = 0; tap < 9; tap++) {
            v8s A[4];
            #pragma unroll
            for (int mt = 0; mt < 4; mt++)
                A[mt] = *(const v8s*)&w2p[(mt * 16 + n) * 288 + tap * 32 + quad * 8];
            #pragma unroll
            for (int nt = 0; nt < 4; nt++) {
                const int row = nt * 16 + n + tap;
                v8s Bf = *(const v8s*)&h1t[((wv * 4 + quad) * 72 + row) * 8];
                #pragma unroll
                for (int mt = 0; mt < 4; mt++)
                    acc[mt][nt] = __builtin_amdgcn_mfma_f32_16x16x32_bf16(A[mt], Bf, acc[mt][nt], 0, 0, 0);
            }
        }
        #pragma unroll
        for (int mt = 0; mt < 4; mt++) {
            float bias[4];
            #pragma unroll
            for (int r = 0; r < 4; r++) bias[r] = b2g[d * 64 + mt * 16 + quad * 4 + r];
            const int gch = mt * 2 + (quad >> 1);       // o-chunk (o>>3)
            const int off = (quad & 1) * 4;
            #pragma unroll
            for (int nt = 0; nt < 4; nt++) {
                const int praw = nt * 16 + n;
                float hv[4];
                #pragma unroll
                for (int r = 0; r < 4; r++) {
                    float v0 = acc[mt][nt][r] + bias[r];
                    float v1 = __shfl_xor(v0, 1);
                    hv[r] = fmaxf(fmaxf(v0, v1), 0.f);
                }
                if (!(praw & 1) && praw < 52) {
                    const int p = praw >> 1;
                    const int gs = gch ^ (p & 7);       // XOR bank swizzle
                    uint2 pkv; pkv.x = pk2(hv[0], hv[1]); pkv.y = pk2(hv[2], hv[3]);
                    *(uint2*)&h2p[wv * 1672 + p * 64 + gs * 8 + off] = pkv;
                }
            }
        }
    }
    __syncthreads();

    // ---- phase 4: fc via MFMA. M=16(l,12 used), N=16(b,8 used), K=1664. ----
    {
        const int n = lane & 15, quad = lane >> 4;
        int lrow = (n < 12) ? n : 0;                  // pad l rows by duplication
        const short* fr = fcwp + ((size_t)d * 12) * 1664;
        v4f acc = {0.f, 0.f, 0.f, 0.f};
        for (int ks = wv; ks < 52; ks += 8) {
            const int p = ks >> 1;
            const int gs = ((ks & 1) * 4 + quad) ^ (p & 7);   // match writer swizzle
            v8s A  = *(const v8s*)&fr[lrow * 1664 + ks * 32 + quad * 8];
            v8s Bf = *(const v8s*)&h2p[(n & 7) * 1672 + p * 64 + gs * 8];
            acc = __builtin_amdgcn_mfma_f32_16x16x32_bf16(A, Bf, acc, 0, 0, 0);
        }
        // ldsA is free: last h1t read completed before the post-phase3 barrier
        *(float4*)&red[(wv * 64 + lane) * 4] = *(float4*)&acc;
    }
    __syncthreads();
    if (t < 64) {
        const int n = lane & 15, quad = lane >> 4;
        float sum[4] = {0.f, 0.f, 0.f, 0.f};
        #pragma unroll
        for (int w = 0; w < 8; w++) {
            float4 v = *(const float4*)&red[(w * 64 + lane) * 4];
            sum[0] += v.x; sum[1] += v.y; sum[2] += v.z; sum[3] += v.w;
        }
        if (n < 8) {
            const float wgt = wts[(size_t)(b0 + n) * 8 + d];
            #pragma unroll
            for (int r = 0; r < 4; r++) {
                const int l = quad * 4 + r;
                if (l < 12) {
                    float v = fmaxf(sum[r] + fcb[d * 12 + l], 0.f);
                    atomicAdd(&out[(size_t)(b0 + n) * 12 + l], wgt * v);
                }
            }
        }
    }
}

extern "C" void kernel_launch(void* const* d_in, const int* in_sizes, int n_in,
                              void* d_out, int out_size, void* d_ws, size_t ws_size,
                              hipStream_t stream) {
    const float* x       = (const float*)d_in[0];
    const float* weights = (const float*)d_in[1];
    const float* gamma   = (const float*)d_in[2];
    const float* beta    = (const float*)d_in[3];
    const float* w1      = (const float*)d_in[4];
    const float* b1      = (const float*)d_in[5];
    const float* w2      = (const float*)d_in[6];
    const float* b2      = (const float*)d_in[7];
    const float* fcw     = (const float*)d_in[8];
    const float* fcb     = (const float*)d_in[9];
    float* ws  = (float*)d_ws;
    float* out = (float*)d_out;

    (void)hipMemsetAsync(ws, 0, 18 * sizeof(float), stream);                // stats bins
    (void)hipMemsetAsync(out, 0, (size_t)out_size * sizeof(float), stream); // atomic dst
    stats_repack_kernel<<<dim3(616), 256, 0, stream>>>(x, w2, fcw, ws);
    fold1_kernel<<<dim3(D), 256, 0, stream>>>(w1, b1, gamma, beta, ws);
    branch_kernel<<<dim3(B / 8, D), 512, 0, stream>>>(x, b2, fcb, weights, ws, out);
}

// Round 7
// 236.039 us; speedup vs baseline: 5.8561x; 1.3029x over previous
//
#include <hip/hip_runtime.h>
#include <hip/hip_bf16.h>

#define D 8
#define L 12
#define C 9
#define W 128
#define B 4096
#define EPS 1e-5f

typedef __attribute__((ext_vector_type(8))) short v8s;   // 8 x bf16
typedef __attribute__((ext_vector_type(4))) float v4f;   // 4 x f32 acc

// Workspace layout (in floats)
#define OFF_STATS 0        // [64 slices][18] per-slice partials (sum[9], sumsq[9])
#define OFF_B1E   1152     // fp32 [D][32] folded conv1 bias
#define OFF_W1T   1408     // bf16 [D][32 o][10 tap][16 c]  = 40960 halfs
#define OFF_W2T   21888    // bf16 [D][64 o][9 tap][32 ic]  = 147456 halfs
#define OFF_FCWP  95616    // bf16 [D][12 l][1664 k=p*64+o] = 159744 halfs

__device__ inline unsigned short f2bf(float f) {
    unsigned u = __builtin_bit_cast(unsigned, f);
    u += 0x7FFFu + ((u >> 16) & 1u);                 // round-nearest-even
    return (unsigned short)(u >> 16);
}
__device__ inline unsigned pk2(float a, float b) {
    float2 f2; f2.x = a; f2.y = b;
    __hip_bfloat162 h = __float22bfloat162_rn(f2);   // v_cvt_pk_bf16_f32
    unsigned u; __builtin_memcpy(&u, &h, 4);
    return u;
}

// ---------------------------------------------------------------------------
// Kernel 1: stats partials (blocks 0..575, no atomics -> no memset needed)
// + w2t/fcwp bf16 repack (blocks 576..615).
// ---------------------------------------------------------------------------
__global__ void stats_repack_kernel(const float* __restrict__ x,
                                    const float* __restrict__ w2,
                                    const float* __restrict__ fcw,
                                    float* __restrict__ ws) {
    const int t = threadIdx.x;
    __shared__ float redS[8];
    if (blockIdx.x < 576) {
        const int c = blockIdx.x % 9;
        const int slice = blockIdx.x / 9;
        const int w4 = t & 31, br = t >> 5;
        const float4* x4 = (const float4*)x;
        float s = 0.f, s2 = 0.f;
        for (int b = slice * 8 + br; b < B; b += 64 * 8) {
            float4 v = x4[(size_t)b * 288 + c * 32 + w4];
            s  += v.x + v.y + v.z + v.w;
            s2 += v.x * v.x + v.y * v.y + v.z * v.z + v.w * v.w;
        }
        for (int off = 32; off >= 1; off >>= 1) {
            s  += __shfl_down(s, off);
            s2 += __shfl_down(s2, off);
        }
        if ((t & 63) == 0) { redS[(t >> 6) * 2] = s; redS[(t >> 6) * 2 + 1] = s2; }
        __syncthreads();
        if (t == 0) {
            ws[OFF_STATS + slice * 18 + c]     = redS[0] + redS[2] + redS[4] + redS[6];
            ws[OFF_STATS + slice * 18 + 9 + c] = redS[1] + redS[3] + redS[5] + redS[7];
        }
    } else {
        const int i0 = blockIdx.x - 576;
        const int d = i0 / 5, part = i0 % 5;
        short* w2t  = (short*)(ws + OFF_W2T);
        short* fcwp = (short*)(ws + OFF_FCWP);
        if (part < 2) {
            for (int i = part * 256 + t; i < 64 * 9 * 32; i += 512) {
                int o = i / 288, r = i % 288, tap = r / 32, ic = r & 31;
                w2t[(size_t)d * 18432 + i] =
                    (short)f2bf(w2[(((size_t)(d * 64 + o)) * 32 + ic) * 9 + tap]);
            }
        } else {
            for (int i = (part - 2) * 256 + t; i < 12 * 1664; i += 768) {
                int l = i / 1664, k = i % 1664, p = k >> 6, o = k & 63;
                fcwp[((size_t)d * 12) * 1664 + i] =
                    (short)f2bf(fcw[((size_t)(d * 12 + l)) * 1664 + o * 26 + p]);
            }
        }
    }
}

// ---------------------------------------------------------------------------
// Kernel 2: reduce slice partials -> BN scale/shift; fold into conv1 weights.
// ---------------------------------------------------------------------------
__global__ void fold1_kernel(const float* __restrict__ w1, const float* __restrict__ b1,
                             const float* __restrict__ gamma, const float* __restrict__ beta,
                             float* __restrict__ ws) {
    const int d = blockIdx.x, t = threadIdx.x;
    __shared__ float g[9], bt[9];
    if (t < 64) {
        for (int c = 0; c < 9; c++) {
            float s  = ws[OFF_STATS + t * 18 + c];
            float s2 = ws[OFF_STATS + t * 18 + 9 + c];
            for (int off = 32; off >= 1; off >>= 1) {
                s  += __shfl_down(s, off);
                s2 += __shfl_down(s2, off);
            }
            if (t == 0) {
                const float N = (float)B * (float)W;
                float m  = s / N;
                float vv = s2 / N - m * m;
                float inv = rsqrtf(vv + EPS);
                float gg = gamma[d * 9 + c] * inv;
                g[c] = gg; bt[c] = beta[d * 9 + c] - gg * m;
            }
        }
    }
    __syncthreads();
    const int o = t >> 3, sub = t & 7;
    short* w1t = (short*)(ws + OFF_W1T);
    short* dst = w1t + (size_t)d * 5120 + o * 160;
    const float* src = w1 + ((size_t)(d * 32 + o)) * 81;
    float bias_part = 0.f;
    for (int tap = sub; tap < 10; tap += 8) {
        for (int c = 0; c < 16; c++) {
            float v = 0.f;
            if (tap < 9 && c < 9) {
                float wv = src[c * 9 + tap];
                v = wv * g[c];
                bias_part += wv * bt[c];
            }
            dst[tap * 16 + c] = (short)f2bf(v);
        }
    }
    bias_part += __shfl_xor(bias_part, 1);
    bias_part += __shfl_xor(bias_part, 2);
    bias_part += __shfl_xor(bias_part, 4);
    if (sub == 0) ws[OFF_B1E + d * 32 + o] = b1[d * 32 + o] + bias_part;
}

// ---------------------------------------------------------------------------
// Kernel 3: the branch. Block = 4 batch rows x 1 domain, 256 threads (4 waves),
// wave wv owns batch row wv. Operand roles: activations = A (M = positions),
// weights = B (N = out-channels). C rows (quad*4+r, in-lane) = positions ->
// maxpool folds in-lane, no cross-lane shuffles in conv epilogues.
// LDS 36.3 KB -> 4 blocks/CU, 4 independent barrier domains.
//   ldsB: xb [4 b][2 ql][144 row][8]  -> h2p [4 b][1672 k] (XOR-swizzled)
//   ldsA: h1t [4b x 4 icq][73 row][8] -> red f32 [4][64][4]
// ---------------------------------------------------------------------------
__global__ __launch_bounds__(256, 4)
void branch_kernel(const float* __restrict__ x,
                   const float* __restrict__ b2g,
                   const float* __restrict__ fcb,
                   const float* __restrict__ wts,
                   const float* __restrict__ ws,
                   float* __restrict__ out) {
    const int t = threadIdx.x;
    const int lane = t & 63;
    const int wv = __builtin_amdgcn_readfirstlane(t >> 6);   // 0..3
    const int d = blockIdx.y;
    const int b0 = blockIdx.x * 4;
    const short* w1t  = (const short*)(ws + OFF_W1T) + (size_t)d * 5120;
    const short* w2t  = (const short*)(ws + OFF_W2T) + (size_t)d * 18432;
    const short* fcwp = (const short*)(ws + OFF_FCWP) + (size_t)d * 12 * 1664;
    const float* b1e  = ws + OFF_B1E + d * 32;

    __shared__ __align__(16) short ldsB[9216];   // 18,432 B
    __shared__ __align__(16) short ldsA[9344];   // 18,688 B
    short* xb  = ldsB;
    short* h1t = ldsA;
    short* h2p = ldsB;                 // aliases xb (dead after phase 2)
    float* red = (float*)ldsA;         // aliases h1t (dead after phase 3)

    const int n = lane & 15, quad = lane >> 4;

    // ---- phase 1: load x transposed straight from global (lanes = w) ----
    {
        const float* xrow = x + (size_t)(b0 + wv) * 1152;
        #pragma unroll
        for (int rep = 0; rep < 2; rep++) {
            const int w = lane + rep * 64;
            float v[9];
            #pragma unroll
            for (int c = 0; c < 9; c++) v[c] = xrow[c * 128 + w];
            uint4 lo, hi;
            lo.x = pk2(v[0], v[1]); lo.y = pk2(v[2], v[3]);
            lo.z = pk2(v[4], v[5]); lo.w = pk2(v[6], v[7]);
            hi.x = (unsigned)(unsigned short)f2bf(v[8]); hi.y = 0; hi.z = 0; hi.w = 0;
            *(uint4*)&xb[((wv * 2 + 0) * 144 + w) * 8] = lo;
            *(uint4*)&xb[((wv * 2 + 1) * 144 + w) * 8] = hi;
        }
        if (lane < 16) {   // zero pad rows 128..143, both planes
            uint4 z; z.x = z.y = z.z = z.w = 0;
            *(uint4*)&xb[((wv * 2 + 0) * 144 + 128 + lane) * 8] = z;
            *(uint4*)&xb[((wv * 2 + 1) * 144 + 128 + lane) * 8] = z;
        }
    }
    __syncthreads();

    // ---- phase 2: conv1. M=128 raw pos (8 tiles), N=32 oc (2 tiles),
    //      K=5 steps of (2 taps x 16 c). In-lane pool -> h1t b16 writes. ----
    {
        const int qh = quad >> 1, ql = quad & 1;
        v4f acc[8][2];
        #pragma unroll
        for (int mt = 0; mt < 8; mt++)
            #pragma unroll
            for (int nt = 0; nt < 2; nt++) { v4f z = {0.f,0.f,0.f,0.f}; acc[mt][nt] = z; }
        const float bias0 = b1e[n], bias1 = b1e[16 + n];
        #pragma unroll
        for (int s = 0; s < 5; s++) {
            v8s Bw0 = *(const v8s*)&w1t[n * 160 + (2 * s + qh) * 16 + ql * 8];
            v8s Bw1 = *(const v8s*)&w1t[(16 + n) * 160 + (2 * s + qh) * 16 + ql * 8];
            #pragma unroll
            for (int mt = 0; mt < 8; mt++) {
                const int row = mt * 16 + n + 2 * s + qh;
                v8s Af = *(const v8s*)&xb[((wv * 2 + ql) * 144 + row) * 8];
                acc[mt][0] = __builtin_amdgcn_mfma_f32_16x16x32_bf16(Af, Bw0, acc[mt][0], 0, 0, 0);
                acc[mt][1] = __builtin_amdgcn_mfma_f32_16x16x32_bf16(Af, Bw1, acc[mt][1], 0, 0, 0);
            }
        }
        #pragma unroll
        for (int mt = 0; mt < 8; mt++) {
            const int p = mt * 8 + quad * 2;    // pooled position of acc rows 0,1
            #pragma unroll
            for (int nt = 0; nt < 2; nt++) {
                const float bb = nt ? bias1 : bias0;
                float h0  = fmaxf(fmaxf(acc[mt][nt][0], acc[mt][nt][1]) + bb, 0.f);
                float h1v = fmaxf(fmaxf(acc[mt][nt][2], acc[mt][nt][3]) + bb, 0.f);
                unsigned pr = pk2(h0, h1v);
                const int plane = wv * 4 + nt * 2 + (n >> 3);   // ic-chunk of conv2
                const int col = n & 7;
                if (p < 60)     h1t[(plane * 73 + p) * 8 + col]     = (short)(pr & 0xFFFFu);
                if (p + 1 < 60) h1t[(plane * 73 + p + 1) * 8 + col] = (short)(pr >> 16);
            }
        }
    }
    __syncthreads();

    // ---- phase 3: conv2. M=64 raw pos (4 tiles), N=64 oc (4 tiles),
    //      K=9 taps x 32 ic. In-lane pool -> h2p (XOR-swizzled). ----
    {
        v4f acc[4][4];
        #pragma unroll
        for (int mt = 0; mt < 4; mt++)
            #pragma unroll
            for (int nt = 0; nt < 4; nt++) { v4f z = {0.f,0.f,0.f,0.f}; acc[mt][nt] = z; }
        float biasv[4];
        #pragma unroll
        for (int nt = 0; nt < 4; nt++) biasv[nt] = b2g[d * 64 + nt * 16 + n];
        for (int tap = 0; tap < 9; tap++) {
            v8s Bw[4];
            #pragma unroll
            for (int nt = 0; nt < 4; nt++)
                Bw[nt] = *(const v8s*)&w2t[(nt * 16 + n) * 288 + tap * 32 + quad * 8];
            #pragma unroll
            for (int mt = 0; mt < 4; mt++) {
                const int row = mt * 16 + n + tap;
                v8s Af = *(const v8s*)&h1t[((wv * 4 + quad) * 73 + row) * 8];
                #pragma unroll
                for (int nt = 0; nt < 4; nt++)
                    acc[mt][nt] = __builtin_amdgcn_mfma_f32_16x16x32_bf16(Af, Bw[nt], acc[mt][nt], 0, 0, 0);
            }
        }
        #pragma unroll
        for (int mt = 0; mt < 4; mt++) {
            const int p = mt * 8 + quad * 2;
            #pragma unroll
            for (int nt = 0; nt < 4; nt++) {
                float h0  = fmaxf(fmaxf(acc[mt][nt][0], acc[mt][nt][1]) + biasv[nt], 0.f);
                float h1v = fmaxf(fmaxf(acc[mt][nt][2], acc[mt][nt][3]) + biasv[nt], 0.f);
                unsigned pr = pk2(h0, h1v);
                const int oc = nt * 16 + n;
                if (p < 26) {
                    const int gs = (oc >> 3) ^ (p & 7);
                    h2p[wv * 1672 + p * 64 + gs * 8 + (oc & 7)] = (short)(pr & 0xFFFFu);
                }
                if (p + 1 < 26) {
                    const int gs = (oc >> 3) ^ ((p + 1) & 7);
                    h2p[wv * 1672 + (p + 1) * 64 + gs * 8 + (oc & 7)] = (short)(pr >> 16);
                }
            }
        }
    }
    __syncthreads();

    // ---- phase 4: fc via MFMA. M=16(l,12 used), N=16(b,4 used), K=1664,
    //      52 ksteps strided over 4 waves; fp32 partials reduced via LDS. ----
    {
        const int lrow = (n < 12) ? n : 0;
        v4f acc = {0.f, 0.f, 0.f, 0.f};
        for (int ks = wv; ks < 52; ks += 4) {
            const int p = ks >> 1;
            const int gs = ((ks & 1) * 4 + quad) ^ (p & 7);   // match writer swizzle
            v8s A  = *(const v8s*)&fcwp[lrow * 1664 + ks * 32 + quad * 8];
            v8s Bf = *(const v8s*)&h2p[(n & 3) * 1672 + p * 64 + gs * 8];
            acc = __builtin_amdgcn_mfma_f32_16x16x32_bf16(A, Bf, acc, 0, 0, 0);
        }
        *(float4*)&red[(wv * 64 + lane) * 4] = *(float4*)&acc;
    }
    __syncthreads();
    if (t < 64) {
        float sum[4] = {0.f, 0.f, 0.f, 0.f};
        #pragma unroll
        for (int w = 0; w < 4; w++) {
            float4 v = *(const float4*)&red[(w * 64 + lane) * 4];
            sum[0] += v.x; sum[1] += v.y; sum[2] += v.z; sum[3] += v.w;
        }
        if (n < 4) {
            const float wgt = wts[(size_t)(b0 + n) * 8 + d];
            #pragma unroll
            for (int r = 0; r < 4; r++) {
                const int l = quad * 4 + r;
                if (l < 12) {
                    float v = fmaxf(sum[r] + fcb[d * 12 + l], 0.f);
                    atomicAdd(&out[(size_t)(b0 + n) * 12 + l], wgt * v);
                }
            }
        }
    }
}

extern "C" void kernel_launch(void* const* d_in, const int* in_sizes, int n_in,
                              void* d_out, int out_size, void* d_ws, size_t ws_size,
                              hipStream_t stream) {
    const float* x       = (const float*)d_in[0];
    const float* weights = (const float*)d_in[1];
    const float* gamma   = (const float*)d_in[2];
    const float* beta    = (const float*)d_in[3];
    const float* w1      = (const float*)d_in[4];
    const float* b1      = (const float*)d_in[5];
    const float* w2      = (const float*)d_in[6];
    const float* b2      = (const float*)d_in[7];
    const float* fcw     = (const float*)d_in[8];
    const float* fcb     = (const float*)d_in[9];
    float* ws  = (float*)d_ws;
    float* out = (float*)d_out;

    (void)hipMemsetAsync(out, 0, (size_t)out_size * sizeof(float), stream); // atomic dst
    stats_repack_kernel<<<dim3(616), 256, 0, stream>>>(x, w2, fcw, ws);
    fold1_kernel<<<dim3(D), 256, 0, stream>>>(w1, b1, gamma, beta, ws);
    branch_kernel<<<dim3(B / 4, D), 256, 0, stream>>>(x, b2, fcb, weights, ws, out);
}